// Round 1
// baseline (5504.192 us; speedup 1.0000x reference)
//
#include <hip/hip_runtime.h>
#include <stdint.h>

// ---------------------------------------------------------------------------
// LSTM decoder: B=256, S=1024, H=256, 4H=1024 gates (i,f,g,o).
// Strategy:
//   P1 pack_x_k : seq_in (h0 | x[:, :-1]) -> bf16, MFMA-A-fragment-packed.
//   P2 pack_misc: W_ih/W_hh -> bf16 B-fragment-packed; bias sum; h0/c0 state.
//   fused_k x9  : blocks 0-15  = persistent LSTM (16 batch rows each, 128
//                 steps/launch, W_hh kt0-1 LDS-resident + kt2-7 streamed);
//                 blocks 16+   = x_proj GEMM for the NEXT chunk (hidden
//                 under the LSTM phase on the other 240 CUs).
// No inter-block sync anywhere (batch-split recurrence is independent).
// ---------------------------------------------------------------------------

using bf16x8 = __attribute__((ext_vector_type(8))) __bf16;
using f32x4  = __attribute__((ext_vector_type(4))) float;
using u32x4  = __attribute__((ext_vector_type(4))) uint32_t;
using u16x2  = __attribute__((ext_vector_type(2))) uint16_t;

#define B_   256
#define S_   1024
#define H_   256
#define NG_  1024
#define CHUNK 128
#define NCHUNK 8

// workspace layout (bytes)
#define XS_OFF   0ull                                   // 16384 m16-tiles * 8 kt * 1KB
#define XS_SZ    134217728ull
#define WIH_OFF  (XS_OFF + XS_SZ)
#define W_SZ     524288ull                              // 64 nt * 8 kt * 1KB
#define WHH_OFF  (WIH_OFF + W_SZ)
#define XP0_OFF  (WHH_OFF + W_SZ)
#define XP_SZ    67108864ull                            // 256*128*1024 bf16
#define XP1_OFF  (XP0_OFF + XP_SZ)
#define HST_OFF  (XP1_OFF + XP_SZ)                      // 16 blk * 8KB
#define HST_SZ   131072ull
#define CST_OFF  (HST_OFF + HST_SZ)                     // 16*8*64*8 fp32
#define CST_SZ   262144ull
#define BIAS_OFF (CST_OFF + CST_SZ)

#define LDS_BYTES 147456   // 128KB resident W + 2*8KB h double-buffer

__device__ __forceinline__ uint16_t f2bf(float f) {
  uint32_t x = __float_as_uint(f);
  x += 0x7fffu + ((x >> 16) & 1u);
  return (uint16_t)(x >> 16);
}
__device__ __forceinline__ float bf2f(uint16_t u) {
  return __uint_as_float(((uint32_t)u) << 16);
}
__device__ __forceinline__ float frcp(float x) { return __builtin_amdgcn_rcpf(x); }
__device__ __forceinline__ float sigm(float x) { return frcp(1.f + __expf(-x)); }
__device__ __forceinline__ float tanh_(float x) { return 1.f - 2.f * frcp(1.f + __expf(2.f * x)); }

__device__ __forceinline__ f32x4 mfma16(u32x4 a, u32x4 b, f32x4 c) {
  return __builtin_amdgcn_mfma_f32_16x16x32_bf16(
      __builtin_bit_cast(bf16x8, a), __builtin_bit_cast(bf16x8, b), c, 0, 0, 0);
}

// ---------------------------------------------------------------------------
// P1: pack shifted input sequence into A-fragment layout.
// xs_pack[m16][kt][lane][8bf16], m = b*1024+s, row of frag = m16*16+(lane&15),
// k = kt*32+(lane>>4)*8..+8.  LDS tile XOR-swizzled to keep both sides fast.
// ---------------------------------------------------------------------------
__global__ __launch_bounds__(256) void pack_x_k(const float* __restrict__ x,
                                                const float* __restrict__ hn,
                                                uint16_t* __restrict__ xsp) {
  __shared__ uint16_t tile[64 * 256];   // 32KB, swizzled
  const int t = blockIdx.x;             // 0..2047 : rows t*128..
  const int tid = threadIdx.x;
  for (int pass = 0; pass < 2; ++pass) {
    const int r = tid >> 2;             // 0..63
    const int qq = tid & 3;             // k quarter
    const int m = t * 128 + pass * 64 + r;
    const int b = m >> 10, s = m & 1023;
    const float* src = s ? (x + (size_t)(b * 1024 + (s - 1)) * 256)
                         : (hn + (size_t)b * 256);
#pragma unroll
    for (int i = 0; i < 64; i += 2) {
      float2 v = *(const float2*)(src + qq * 64 + i);
      uint32_t kb = (uint32_t)(qq * 64 + i) * 2u;
      uint32_t addr = (uint32_t)r * 512u + (kb ^ (((uint32_t)r & 7u) << 4));
      u16x2 pr; pr.x = f2bf(v.x); pr.y = f2bf(v.y);
      *(u16x2*)((char*)tile + addr) = pr;
    }
    __syncthreads();
#pragma unroll
    for (int ff = 0; ff < 8; ++ff) {
      int task = ff * 256 + tid;        // 2048 tasks = 32 frags * 64 lanes
      int frag = task >> 6, lam = task & 63;
      int mt = frag >> 3, kt = frag & 7;
      int row = mt * 16 + (lam & 15);
      uint32_t kb = (uint32_t)(kt * 64 + (lam >> 4) * 16);
      u32x4 d = *(const u32x4*)((const char*)tile + row * 512 +
                                (kb ^ (((uint32_t)row & 7u) << 4)));
      size_t m16 = (size_t)t * 8 + pass * 4 + mt;
      *(u32x4*)(xsp + ((m16 * 8 + kt) * 64 + lam) * 8) = d;
    }
    __syncthreads();
  }
}

// ---------------------------------------------------------------------------
// P2: pack W_ih/W_hh into B-fragment layout (lane holds W[n=nt*16+(l&15)][8k]),
// bias sum, h0 (bf16 A-frag packed per LSTM block), c0 (per-lane layout).
// ---------------------------------------------------------------------------
__global__ __launch_bounds__(256) void pack_misc_k(
    const float* __restrict__ wih, const float* __restrict__ whh,
    const float* __restrict__ bih, const float* __restrict__ bhh,
    const float* __restrict__ hn, const float* __restrict__ cn,
    uint16_t* __restrict__ wihp, uint16_t* __restrict__ whhp,
    float* __restrict__ bias, uint16_t* __restrict__ hst, float* __restrict__ cst) {
  const int blk = blockIdx.x, tid = threadIdx.x;
  if (blk < 32) {
    __shared__ uint16_t tile[64 * 256];
    const float* W = (blk < 16) ? wih : whh;
    uint16_t* WP = (blk < 16) ? wihp : whhp;
    const int rowbase = (blk & 15) * 64;
    const int r = tid >> 2, qq = tid & 3;
    const float* src = W + (size_t)(rowbase + r) * 256;
#pragma unroll
    for (int i = 0; i < 64; i += 2) {
      float2 v = *(const float2*)(src + qq * 64 + i);
      uint32_t kb = (uint32_t)(qq * 64 + i) * 2u;
      uint32_t addr = (uint32_t)r * 512u + (kb ^ (((uint32_t)r & 7u) << 4));
      u16x2 pr; pr.x = f2bf(v.x); pr.y = f2bf(v.y);
      *(u16x2*)((char*)tile + addr) = pr;
    }
    __syncthreads();
#pragma unroll
    for (int ff = 0; ff < 8; ++ff) {
      int task = ff * 256 + tid;
      int frag = task >> 6, lam = task & 63;
      int mt = frag >> 3, kt = frag & 7;
      int row = mt * 16 + (lam & 15);
      uint32_t kb = (uint32_t)(kt * 64 + (lam >> 4) * 16);
      u32x4 d = *(const u32x4*)((const char*)tile + row * 512 +
                                (kb ^ (((uint32_t)row & 7u) << 4)));
      size_t nt = (size_t)(blk & 15) * 4 + mt;
      *(u32x4*)(WP + ((nt * 8 + kt) * 64 + lam) * 8) = d;
    }
  } else if (blk == 32) {
    for (int i = tid; i < 4096; i += 256) bias[i] = bih[i] + bhh[i];
  } else if (blk == 33) {
    // h_state[lblk][kt][lam][8]
    for (int it = 0; it < 32; ++it) {
      int task = it * 256 + tid;
      int lam = task & 63;
      int kt = (task >> 6) & 7;
      int lb = task >> 9;
      int b = lb * 16 + (lam & 15);
      int k0 = kt * 32 + (lam >> 4) * 8;
      union { uint16_t s[8]; u32x4 v; } u;
#pragma unroll
      for (int j = 0; j < 8; ++j) u.s[j] = f2bf(hn[(size_t)b * 256 + k0 + j]);
      *(u32x4*)(hst + (size_t)task * 8) = u.v;
    }
  } else {
    // blk 34,35: c_state[lblk][w][lane][v], v = jt*4+q
    for (int it = 0; it < 16; ++it) {
      int lt = it * 512 + (blk - 34) * 256 + tid;
      int l = lt & 63;
      int w = (lt >> 6) & 7;
      int lb = lt >> 9;
#pragma unroll
      for (int v = 0; v < 8; ++v) {
        int q = v & 3, jt = v >> 2;
        int bb = lb * 16 + (l >> 4) * 4 + q;
        int j = w * 32 + jt * 16 + (l & 15);
        cst[(size_t)lt * 8 + v] = cn[(size_t)bb * 256 + j];
      }
    }
  }
}

// ---------------------------------------------------------------------------
// fused: blocks 0-15 persistent LSTM chunk `lstm_chunk`;
//        blocks 16..2063 x_proj GEMM chunk `gemm_chunk` (128x128 tiles).
// ---------------------------------------------------------------------------
__global__ __launch_bounds__(512, 2) void fused_k(
    const uint16_t* __restrict__ xsp, const uint16_t* __restrict__ wihp,
    const uint16_t* __restrict__ whhp, const float* __restrict__ bias,
    uint16_t* __restrict__ xp0, uint16_t* __restrict__ xp1,
    uint16_t* __restrict__ hst, float* __restrict__ cst,
    float* __restrict__ out, int lstm_chunk, int gemm_chunk) {
  extern __shared__ __align__(16) char lds[];
  const int tid = threadIdx.x;
  const int lane = tid & 63;
  const int w = tid >> 6;

  if (blockIdx.x < 16) {
    // ======================= LSTM path =======================
    if (lstm_chunk < 0) return;
    const int c = lstm_chunk;
    const int blk = blockIdx.x;
    const int b0 = blk * 16;
    const uint16_t* __restrict__ xp = (c & 1) ? xp1 : xp0;

    // resident W_hh: kt 0,1 for this wave's 8 n-frags
#pragma unroll
    for (int f = 0; f < 8; ++f) {
      int nt = (f >> 1) * 16 + w * 2 + (f & 1);   // n = g*256 + w*32 + jt*16
#pragma unroll
      for (int kt = 0; kt < 2; ++kt) {
        u32x4 d = *(const u32x4*)(whhp + ((size_t)(nt * 8 + kt) * 64 + lane) * 8);
        *(u32x4*)(lds + w * 16384 + (f * 2 + kt) * 1024 + lane * 16) = d;
      }
    }
    // h state -> buffer 0 (tid = kt*64+lam over 512 threads)
    {
      u32x4 hd = *(const u32x4*)(hst + (size_t)blk * 4096 + (size_t)tid * 8);
      *(u32x4*)(lds + 131072 + tid * 16) = hd;
    }
    // c registers
    float creg[8];
    {
      const float* cs = cst + ((size_t)(blk * 8 + w) * 64 + lane) * 8;
#pragma unroll
      for (int v = 0; v < 8; ++v) creg[v] = cs[v];
    }
    // stream base pointers (kt 2..7 fetched per step)
    const uint16_t* wbase[8];
#pragma unroll
    for (int f = 0; f < 8; ++f) {
      int nt = (f >> 1) * 16 + w * 2 + (f & 1);
      wbase[f] = whhp + (size_t)nt * 4096 + (size_t)lane * 8;
    }
    // xp / out pointers per q (row m = (lane>>4)*4+q)
    const uint16_t* xq[4];
    float* oq[4];
#pragma unroll
    for (int q = 0; q < 4; ++q) {
      int mq = (lane >> 4) * 4 + q;
      xq[q] = xp + (size_t)(b0 + mq) * 128 * 1024 + w * 32 + (lane & 15);
      oq[q] = out + ((size_t)(b0 + mq) * 1024 + (size_t)c * 128) * 256 + w * 32 + (lane & 15);
    }
    __syncthreads();

    int p = 0;
#pragma unroll 1
    for (int s = 0; s < 128; ++s) {
      // prefetch x_proj contributions (32 scalars; hidden under MFMA phase)
      uint16_t xpv[4][2][4];
#pragma unroll
      for (int q = 0; q < 4; ++q)
#pragma unroll
        for (int g = 0; g < 4; ++g)
#pragma unroll
          for (int jt = 0; jt < 2; ++jt)
            xpv[g][jt][q] = xq[q][g * 256 + jt * 16];

      f32x4 acc[8] = {};
      u32x4 bpipe[2][8];
#pragma unroll
      for (int f = 0; f < 8; ++f)
        bpipe[0][f] = *(const u32x4*)(wbase[f] + 2 * 512);
      const char* hb = lds + 131072 + p * 8192 + lane * 16;
#pragma unroll
      for (int kt = 0; kt < 8; ++kt) {
        u32x4 a = *(const u32x4*)(hb + kt * 1024);
        if (kt < 2) {
#pragma unroll
          for (int f = 0; f < 8; ++f) {
            u32x4 bb = *(const u32x4*)(lds + w * 16384 + (f * 2 + kt) * 1024 + lane * 16);
            acc[f] = mfma16(a, bb, acc[f]);
          }
        } else {
          if (kt < 7) {
#pragma unroll
            for (int f = 0; f < 8; ++f)
              bpipe[(kt & 1) ^ 1][f] = *(const u32x4*)(wbase[f] + (kt + 1) * 512);
          }
#pragma unroll
          for (int f = 0; f < 8; ++f) acc[f] = mfma16(a, bpipe[kt & 1][f], acc[f]);
        }
      }
      // cell update (per lane: 2 jt * 4 q values)
      char* hw = lds + 131072 + (p ^ 1) * 8192;
#pragma unroll
      for (int jt = 0; jt < 2; ++jt)
#pragma unroll
        for (int q = 0; q < 4; ++q) {
          float xi = acc[0 + jt][q] + bf2f(xpv[0][jt][q]);
          float xf = acc[2 + jt][q] + bf2f(xpv[1][jt][q]);
          float xg = acc[4 + jt][q] + bf2f(xpv[2][jt][q]);
          float xo = acc[6 + jt][q] + bf2f(xpv[3][jt][q]);
          float I = sigm(xi), F = sigm(xf), T = tanh_(xg), O = sigm(xo);
          float cv = F * creg[jt * 4 + q] + I * T;
          creg[jt * 4 + q] = cv;
          float hv = O * tanh_(cv);
          oq[q][jt * 16] = hv;
          int j = w * 32 + jt * 16 + (lane & 15);
          int m = (lane >> 4) * 4 + q;
          int kt2 = j >> 5, lam2 = ((j >> 3) & 3) * 16 + m;
          *(uint16_t*)(hw + kt2 * 1024 + lam2 * 16 + (j & 7) * 2) = f2bf(hv);
        }
#pragma unroll
      for (int q = 0; q < 4; ++q) { xq[q] += 1024; oq[q] += 256; }
      __syncthreads();
      p ^= 1;
    }
    // write back carry state
    {
      u32x4 hd = *(const u32x4*)(lds + 131072 + p * 8192 + tid * 16);
      *(u32x4*)(hst + (size_t)blk * 4096 + (size_t)tid * 8) = hd;
      float* cs = cst + ((size_t)(blk * 8 + w) * 64 + lane) * 8;
#pragma unroll
      for (int v = 0; v < 8; ++v) cs[v] = creg[v];
    }
    return;
  }

  // ======================= x_proj GEMM path =======================
  if (gemm_chunk < 0) return;
  const int c = gemm_chunk;
  const int bid = blockIdx.x - 16;   // 0..2047
  const int bb = bid >> 3;           // batch 0..255
  const int bn = bid & 7;            // n-tile group (128 cols)
  const int wm = w >> 2, wn = w & 3; // wave -> 64m x 32n
  f32x4 acc[4][2] = {};
#pragma unroll
  for (int kt = 0; kt < 8; ++kt) {
    u32x4 av[4], bv[2];
#pragma unroll
    for (int mt = 0; mt < 4; ++mt) {
      size_t m16 = (size_t)bb * 64 + (size_t)c * 8 + wm * 4 + mt;
      av[mt] = *(const u32x4*)(xsp + ((m16 * 8 + kt) * 64 + lane) * 8);
    }
#pragma unroll
    for (int f = 0; f < 2; ++f) {
      size_t nt = (size_t)bn * 8 + wn * 2 + f;
      bv[f] = *(const u32x4*)(wihp + ((nt * 8 + kt) * 64 + lane) * 8);
    }
#pragma unroll
    for (int mt = 0; mt < 4; ++mt)
#pragma unroll
      for (int f = 0; f < 2; ++f) acc[mt][f] = mfma16(av[mt], bv[f], acc[mt][f]);
  }
  uint16_t* __restrict__ xpo = (c & 1) ? xp1 : xp0;
  float badd[2];
#pragma unroll
  for (int f = 0; f < 2; ++f)
    badd[f] = bias[(bn * 8 + wn * 2 + f) * 16 + (lane & 15)];
#pragma unroll
  for (int mt = 0; mt < 4; ++mt)
#pragma unroll
    for (int f = 0; f < 2; ++f)
#pragma unroll
      for (int q = 0; q < 4; ++q) {
        int mloc = (wm * 4 + mt) * 16 + (lane >> 4) * 4 + q;
        int n = (bn * 8 + wn * 2 + f) * 16 + (lane & 15);
        xpo[((size_t)bb * 128 + mloc) * 1024 + n] = f2bf(acc[mt][f][q] + badd[f]);
      }
}

// ---------------------------------------------------------------------------
extern "C" void kernel_launch(void* const* d_in, const int* in_sizes, int n_in,
                              void* d_out, int out_size, void* d_ws, size_t ws_size,
                              hipStream_t stream) {
  const float* x   = (const float*)d_in[0];
  const float* hn  = (const float*)d_in[1];
  const float* cn  = (const float*)d_in[2];
  const float* wih = (const float*)d_in[3];
  const float* whh = (const float*)d_in[4];
  const float* bih = (const float*)d_in[5];
  const float* bhh = (const float*)d_in[6];
  float* out = (float*)d_out;
  char* ws = (char*)d_ws;

  uint16_t* xsp  = (uint16_t*)(ws + XS_OFF);
  uint16_t* wihp = (uint16_t*)(ws + WIH_OFF);
  uint16_t* whhp = (uint16_t*)(ws + WHH_OFF);
  uint16_t* xp0  = (uint16_t*)(ws + XP0_OFF);
  uint16_t* xp1  = (uint16_t*)(ws + XP1_OFF);
  uint16_t* hst  = (uint16_t*)(ws + HST_OFF);
  float*    cst  = (float*)(ws + CST_OFF);
  float*    bias = (float*)(ws + BIAS_OFF);

  hipFuncSetAttribute(reinterpret_cast<const void*>(fused_k),
                      hipFuncAttributeMaxDynamicSharedMemorySize, LDS_BYTES);

  hipLaunchKernelGGL(pack_x_k, dim3(2048), dim3(256), 0, stream, x, hn, xsp);
  hipLaunchKernelGGL(pack_misc_k, dim3(36), dim3(256), 0, stream,
                     wih, whh, bih, bhh, hn, cn, wihp, whhp, bias, hst, cst);
  for (int c = 0; c <= NCHUNK; ++c) {
    int lc = c - 1;
    int gc = (c < NCHUNK) ? c : -1;
    hipLaunchKernelGGL(fused_k, dim3(2064), dim3(512), LDS_BYTES, stream,
                       xsp, wihp, whhp, bias, xp0, xp1, hst, cst, out, lc, gc);
  }
}

// Round 2
// 2409.634 us; speedup vs baseline: 2.2842x; 2.2842x over previous
//
#include <hip/hip_runtime.h>
#include <stdint.h>

// ---------------------------------------------------------------------------
// LSTM decoder: B=256, S=1024, H=256, 4H=1024 gates (i,f,g,o).
// Round-2 strategy: W_hh fully RESIDENT per LSTM CU (VGPRs + LDS), zero
// per-step global W traffic. 16 LSTM blocks x 8 waves; wave owns js-pair
// (2 hidden 16-col slices) x all 4 gates -> cell update lane-local.
// W/bias pre-scaled by -log2e (-2log2e for g-gate) -> raw v_exp_f32.
// x_proj GEMM (blocks 16..527) writes xpp in the exact per-lane layout the
// LSTM consumes (32B/lane contiguous).
// ---------------------------------------------------------------------------

using bf16x8 = __attribute__((ext_vector_type(8))) __bf16;
using f32x4  = __attribute__((ext_vector_type(4))) float;
using u32x4  = __attribute__((ext_vector_type(4))) uint32_t;
using u16x2  = __attribute__((ext_vector_type(2))) uint16_t;

#define NCHUNK 8

// workspace layout (bytes)
#define XS_OFF   0ull                                   // 16384 m16-tiles * 8 kt * 1KB
#define XS_SZ    134217728ull
#define WIH_OFF  (XS_OFF + XS_SZ)
#define W_SZ     524288ull                              // 64 nt * 8 kt * 1KB
#define WHH_OFF  (WIH_OFF + W_SZ)
#define XP0_OFF  (WHH_OFF + W_SZ)
#define XP_SZ    67108864ull                            // 16*128*16*64*16 bf16 = 64MB
#define XP1_OFF  (XP0_OFF + XP_SZ)
#define HST_OFF  (XP1_OFF + XP_SZ)                      // 16 blk * 8KB
#define HST_SZ   131072ull
#define CST_OFF  (HST_OFF + HST_SZ)                     // 16*8*64*8 fp32
#define CST_SZ   262144ull
#define BIAS_OFF (CST_OFF + CST_SZ)

// LSTM LDS: 8 waves * 17 fkt * 1KB = 139264, then 2 * 8KB h double-buffer
#define WLDS_PER_WAVE 17408
#define HOFF   139264
#define LDS_BYTES 155648

#define SC_IFO -1.442695041f     // -log2(e)
#define SC_G   -2.885390082f     // -2*log2(e)

__device__ __forceinline__ uint16_t f2bf(float f) {
  uint32_t x = __float_as_uint(f);
  x += 0x7fffu + ((x >> 16) & 1u);
  return (uint16_t)(x >> 16);
}
__device__ __forceinline__ float bf2f(uint16_t u) {
  return __uint_as_float(((uint32_t)u) << 16);
}
__device__ __forceinline__ float frcp(float x) { return __builtin_amdgcn_rcpf(x); }
__device__ __forceinline__ float exp2a(float x) {
  float r; asm("v_exp_f32 %0, %1" : "=v"(r) : "v"(x)); return r;
}

__device__ __forceinline__ f32x4 mfma16(u32x4 a, u32x4 b, f32x4 c) {
  return __builtin_amdgcn_mfma_f32_16x16x32_bf16(
      __builtin_bit_cast(bf16x8, a), __builtin_bit_cast(bf16x8, b), c, 0, 0, 0);
}

// W_hh residency map: per wave 64 fkt (f=hs*4+g in 0..7, kt in 0..7)
// regs: kt<5 (all f) + kt==5 & f<7  -> 47 u32x4
// LDS : kt==5 & f==7 -> idx0 ; kt==6 -> 1+f ; kt==7 -> 9+f  -> 17 KB/wave
#define W_IN_REG(f, kt) ((kt) < 5 || ((kt) == 5 && (f) < 7))
#define WIDX(f, kt)     ((f) < 7 ? (f) * 6 + (kt) : 42 + (kt))
#define LIDX(f, kt)     ((kt) == 5 ? 0 : ((kt) - 6) * 8 + 1 + (f))

// ---------------------------------------------------------------------------
// P1: pack shifted input sequence (S-MAJOR rows: r = s*256 + b) into
// A-fragment layout xsp[m16][kt][lane][8bf16].
// ---------------------------------------------------------------------------
__global__ __launch_bounds__(256) void pack_x_k(const float* __restrict__ x,
                                                const float* __restrict__ hn,
                                                uint16_t* __restrict__ xsp) {
  __shared__ uint16_t tile[64 * 256];   // 32KB, swizzled
  const int t = blockIdx.x;             // 0..2047
  const int tid = threadIdx.x;
  for (int pass = 0; pass < 2; ++pass) {
    const int r = tid >> 2;             // 0..63
    const int qq = tid & 3;
    const int rg = t * 128 + pass * 64 + r;    // global row, s-major
    const int s = rg >> 8, b = rg & 255;
    const float* src = s ? (x + ((size_t)b * 1024 + (s - 1)) * 256)
                         : (hn + (size_t)b * 256);
#pragma unroll
    for (int i = 0; i < 64; i += 2) {
      float2 v = *(const float2*)(src + qq * 64 + i);
      uint32_t kb = (uint32_t)(qq * 64 + i) * 2u;
      uint32_t addr = (uint32_t)r * 512u + (kb ^ (((uint32_t)r & 7u) << 4));
      u16x2 pr; pr.x = f2bf(v.x); pr.y = f2bf(v.y);
      *(u16x2*)((char*)tile + addr) = pr;
    }
    __syncthreads();
#pragma unroll
    for (int ff = 0; ff < 8; ++ff) {
      int task = ff * 256 + tid;
      int frag = task >> 6, lam = task & 63;
      int mt = frag >> 3, kt = frag & 7;
      int row = mt * 16 + (lam & 15);
      uint32_t kb = (uint32_t)(kt * 64 + (lam >> 4) * 16);
      u32x4 d = *(const u32x4*)((const char*)tile + row * 512 +
                                (kb ^ (((uint32_t)row & 7u) << 4)));
      size_t m16 = (size_t)t * 8 + pass * 4 + mt;
      *(u32x4*)(xsp + ((m16 * 8 + kt) * 64 + lam) * 8) = d;
    }
    __syncthreads();
  }
}

// ---------------------------------------------------------------------------
// P2: pack W_ih/W_hh (PRE-SCALED by -log2e / -2log2e) into B-frag layout;
// scaled bias sum; h0 A-frag state; c0 per-lane state.
// ---------------------------------------------------------------------------
__global__ __launch_bounds__(256) void pack_misc_k(
    const float* __restrict__ wih, const float* __restrict__ whh,
    const float* __restrict__ bih, const float* __restrict__ bhh,
    const float* __restrict__ hn, const float* __restrict__ cn,
    uint16_t* __restrict__ wihp, uint16_t* __restrict__ whhp,
    float* __restrict__ bias, uint16_t* __restrict__ hst, float* __restrict__ cst) {
  const int blk = blockIdx.x, tid = threadIdx.x;
  if (blk < 32) {
    __shared__ uint16_t tile[64 * 256];
    const float* W = (blk < 16) ? wih : whh;
    uint16_t* WP = (blk < 16) ? wihp : whhp;
    const int rowbase = (blk & 15) * 64;
    const int r = tid >> 2, qq = tid & 3;
    const int n = rowbase + r;
    const float sc = ((n >> 8) == 2) ? SC_G : SC_IFO;
    const float* src = W + (size_t)n * 256;
#pragma unroll
    for (int i = 0; i < 64; i += 2) {
      float2 v = *(const float2*)(src + qq * 64 + i);
      uint32_t kb = (uint32_t)(qq * 64 + i) * 2u;
      uint32_t addr = (uint32_t)r * 512u + (kb ^ (((uint32_t)r & 7u) << 4));
      u16x2 pr; pr.x = f2bf(v.x * sc); pr.y = f2bf(v.y * sc);
      *(u16x2*)((char*)tile + addr) = pr;
    }
    __syncthreads();
#pragma unroll
    for (int ff = 0; ff < 8; ++ff) {
      int task = ff * 256 + tid;
      int frag = task >> 6, lam = task & 63;
      int mt = frag >> 3, kt = frag & 7;
      int row = mt * 16 + (lam & 15);
      uint32_t kb = (uint32_t)(kt * 64 + (lam >> 4) * 16);
      u32x4 d = *(const u32x4*)((const char*)tile + row * 512 +
                                (kb ^ (((uint32_t)row & 7u) << 4)));
      size_t nt = (size_t)(blk & 15) * 4 + mt;
      *(u32x4*)(WP + ((nt * 8 + kt) * 64 + lam) * 8) = d;
    }
  } else if (blk == 32) {
    for (int i = tid; i < 4096; i += 256) {
      float sc = ((i >> 8) == 2) ? SC_G : SC_IFO;
      bias[i] = (bih[i] + bhh[i]) * sc;
    }
  } else if (blk == 33) {
    // h_state[lblk][kt][lam][8] (A-frag layout)
    for (int it = 0; it < 32; ++it) {
      int task = it * 256 + tid;
      int lam = task & 63;
      int kt = (task >> 6) & 7;
      int lb = task >> 9;
      int b = lb * 16 + (lam & 15);
      int k0 = kt * 32 + (lam >> 4) * 8;
      union { uint16_t s[8]; u32x4 v; } u;
#pragma unroll
      for (int j = 0; j < 8; ++j) u.s[j] = f2bf(hn[(size_t)b * 256 + k0 + j]);
      *(u32x4*)(hst + (size_t)task * 8) = u.v;
    }
  } else {
    // blk 34,35: c_state[lblk][w][lane][v], v = hs*4+q
    for (int it = 0; it < 16; ++it) {
      int lt = it * 512 + (blk - 34) * 256 + tid;
      int l = lt & 63;
      int w = (lt >> 6) & 7;
      int lb = lt >> 9;
#pragma unroll
      for (int v = 0; v < 8; ++v) {
        int q = v & 3, hs = v >> 2;
        int bb = lb * 16 + (l >> 4) * 4 + q;
        int j = w * 32 + hs * 16 + (l & 15);
        cst[(size_t)lt * 8 + v] = cn[(size_t)bb * 256 + j];
      }
    }
  }
}

// ---------------------------------------------------------------------------
// fused: blocks 0-15 persistent LSTM chunk `lstm_chunk` (128 steps);
//        blocks 16..527 x_proj GEMM chunk `gemm_chunk`.
// ---------------------------------------------------------------------------
__global__ __launch_bounds__(512, 2) void fused_k(
    const uint16_t* __restrict__ xsp, const uint16_t* __restrict__ wihp,
    const uint16_t* __restrict__ whhp, const float* __restrict__ bias,
    uint16_t* __restrict__ xp0, uint16_t* __restrict__ xp1,
    uint16_t* __restrict__ hst, float* __restrict__ cst,
    float* __restrict__ out, int lstm_chunk, int gemm_chunk) {
  extern __shared__ __align__(16) char lds[];
  const int tid = threadIdx.x;
  const int l = tid & 63;
  const int w = tid >> 6;

  if (blockIdx.x < 16) {
    // ======================= LSTM path =======================
    if (lstm_chunk < 0) return;
    const int c = lstm_chunk;
    const int blk = blockIdx.x;
    const uint16_t* __restrict__ xp = (c & 1) ? xp1 : xp0;

    // ---- W_hh residency: 47 fkt in regs, 17 fkt/wave in LDS ----
    u32x4 wr[47];
#pragma unroll
    for (int f = 0; f < 8; ++f) {
#pragma unroll
      for (int kt = 0; kt < 8; ++kt) {
        int nt = (f & 3) * 16 + (w * 2 + (f >> 2));
        u32x4 d = *(const u32x4*)(whhp + (((size_t)nt * 8 + kt) * 64 + l) * 8);
        if (W_IN_REG(f, kt))
          wr[WIDX(f, kt)] = d;
        else
          *(u32x4*)(lds + w * WLDS_PER_WAVE + LIDX(f, kt) * 1024 + l * 16) = d;
      }
    }
    // h(0) -> buffer 0
    *(u32x4*)(lds + HOFF + tid * 16) =
        *(const u32x4*)(hst + (size_t)blk * 4096 + (size_t)tid * 8);
    // c registers
    float creg[8];
    {
      const float* cs = cst + ((size_t)(blk * 8 + w) * 64 + l) * 8;
#pragma unroll
      for (int v = 0; v < 8; ++v) creg[v] = cs[v];
    }
    // x_proj pointer: 32B per lane per (step, hs-cell)
    const char* xpbase = (const char*)xp +
        ((((size_t)blk * 128) * 16 + (size_t)(w * 2)) * 64 + l) * 32;
    // out base: b = blk*16 + (l>>4)*4 (+q), j = (2w+hs)*16 + (l&15)
    float* ob = out + ((size_t)(blk * 16 + (l >> 4) * 4) * 1024 + (size_t)c * 128) * 256 + (l & 15);
    // h-write base per hs (j constant per lane within hs)
    __syncthreads();

    int p = 0;
#pragma unroll 1
    for (int s = 0; s < 128; ++s) {
      const char* xc = xpbase + (size_t)s * 32768;
      union XV { uint16_t sv[16]; u32x4 v[2]; };
      XV xv0;
      xv0.v[0] = *(const u32x4*)(xc);
      xv0.v[1] = *(const u32x4*)(xc + 16);
      const char* hb = lds + HOFF + p * 8192 + l * 16;
      char* hw = lds + HOFF + (p ^ 1) * 8192;

      // ---------- half-step 0 (js = 2w) ----------
      f32x4 acc0[4] = {};
#pragma unroll
      for (int kt = 0; kt < 8; ++kt) {
        u32x4 a = *(const u32x4*)(hb + kt * 1024);
#pragma unroll
        for (int g = 0; g < 4; ++g) {
          u32x4 b = W_IN_REG(g, kt)
                        ? wr[WIDX(g, kt)]
                        : *(const u32x4*)(lds + w * WLDS_PER_WAVE + LIDX(g, kt) * 1024 + l * 16);
          acc0[g] = mfma16(a, b, acc0[g]);
        }
      }
      // issue hs1 xpv loads now (overlap with hs0 VALU + hs1 MFMA)
      XV xv1;
      xv1.v[0] = *(const u32x4*)(xc + 2048);
      xv1.v[1] = *(const u32x4*)(xc + 2048 + 16);
      {
        const int j = (w * 2) * 16 + (l & 15);
        char* hwj = hw + (j >> 5) * 1024 + (((j >> 3) & 3) * 16) * 16 + (j & 7) * 2;
        float* obh = ob + (size_t)s * 256 + (w * 2) * 16;
#pragma unroll
        for (int q = 0; q < 4; ++q) {
          float xi = acc0[0][q] + bf2f(xv0.sv[0 * 4 + q]);
          float xf = acc0[1][q] + bf2f(xv0.sv[1 * 4 + q]);
          float xg = acc0[2][q] + bf2f(xv0.sv[2 * 4 + q]);
          float xo = acc0[3][q] + bf2f(xv0.sv[3 * 4 + q]);
          float I = frcp(1.f + exp2a(xi));
          float F = frcp(1.f + exp2a(xf));
          float T = fmaf(2.f, frcp(1.f + exp2a(xg)), -1.f);
          float O = frcp(1.f + exp2a(xo));
          float cv = fmaf(F, creg[q], I * T);
          creg[q] = cv;
          float th = fmaf(2.f, frcp(1.f + exp2a(SC_G * cv)), -1.f);
          float hv = O * th;
          obh[(size_t)q * 262144] = hv;
          int m = (l >> 4) * 4 + q;
          *(uint16_t*)(hwj + m * 16) = f2bf(hv);
        }
      }

      // ---------- half-step 1 (js = 2w+1) ----------
      f32x4 acc1[4] = {};
#pragma unroll
      for (int kt = 0; kt < 8; ++kt) {
        u32x4 a = *(const u32x4*)(hb + kt * 1024);
#pragma unroll
        for (int g = 0; g < 4; ++g) {
          u32x4 b = W_IN_REG(4 + g, kt)
                        ? wr[WIDX(4 + g, kt)]
                        : *(const u32x4*)(lds + w * WLDS_PER_WAVE + LIDX(4 + g, kt) * 1024 + l * 16);
          acc1[g] = mfma16(a, b, acc1[g]);
        }
      }
      {
        const int j = (w * 2 + 1) * 16 + (l & 15);
        char* hwj = hw + (j >> 5) * 1024 + (((j >> 3) & 3) * 16) * 16 + (j & 7) * 2;
        float* obh = ob + (size_t)s * 256 + (w * 2 + 1) * 16;
#pragma unroll
        for (int q = 0; q < 4; ++q) {
          float xi = acc1[0][q] + bf2f(xv1.sv[0 * 4 + q]);
          float xf = acc1[1][q] + bf2f(xv1.sv[1 * 4 + q]);
          float xg = acc1[2][q] + bf2f(xv1.sv[2 * 4 + q]);
          float xo = acc1[3][q] + bf2f(xv1.sv[3 * 4 + q]);
          float I = frcp(1.f + exp2a(xi));
          float F = frcp(1.f + exp2a(xf));
          float T = fmaf(2.f, frcp(1.f + exp2a(xg)), -1.f);
          float O = frcp(1.f + exp2a(xo));
          float cv = fmaf(F, creg[4 + q], I * T);
          creg[4 + q] = cv;
          float th = fmaf(2.f, frcp(1.f + exp2a(SC_G * cv)), -1.f);
          float hv = O * th;
          obh[(size_t)q * 262144] = hv;
          int m = (l >> 4) * 4 + q;
          *(uint16_t*)(hwj + m * 16) = f2bf(hv);
        }
      }
      __syncthreads();
      p ^= 1;
    }
    // write back carry state
    *(u32x4*)(hst + (size_t)blk * 4096 + (size_t)tid * 8) =
        *(const u32x4*)(lds + HOFF + p * 8192 + tid * 16);
    {
      float* cs = cst + ((size_t)(blk * 8 + w) * 64 + l) * 8;
#pragma unroll
      for (int v = 0; v < 8; ++v) cs[v] = creg[v];
    }
    return;
  }

  // ======================= x_proj GEMM path =======================
  if (gemm_chunk < 0) return;
  const int c = gemm_chunk;
  const int bid = blockIdx.x - 16;   // 0..511
  const int sg = bid >> 4;           // s-group (4 seq positions)
  const int bb = bid & 15;           // batch group (16 batches)

  f32x4 acc[4][2][4] = {};           // [mt][jj][g]
#pragma unroll
  for (int kt = 0; kt < 8; ++kt) {
    u32x4 av[4];
#pragma unroll
    for (int mt = 0; mt < 4; ++mt) {
      size_t m16 = (size_t)(c * 128 + sg * 4 + mt) * 16 + bb;
      av[mt] = *(const u32x4*)(xsp + ((m16 * 8 + kt) * 64 + l) * 8);
    }
    u32x4 bv[2][4];
#pragma unroll
    for (int jj = 0; jj < 2; ++jj)
#pragma unroll
      for (int g = 0; g < 4; ++g) {
        size_t nt = (size_t)(g * 16 + w * 2 + jj);
        bv[jj][g] = *(const u32x4*)(wihp + ((nt * 8 + kt) * 64 + l) * 8);
      }
#pragma unroll
    for (int mt = 0; mt < 4; ++mt)
#pragma unroll
      for (int jj = 0; jj < 2; ++jj)
#pragma unroll
        for (int g = 0; g < 4; ++g)
          acc[mt][jj][g] = mfma16(av[mt], bv[jj][g], acc[mt][jj][g]);
  }
  uint16_t* __restrict__ xpo = (c & 1) ? xp1 : xp0;
  float badd[2][4];
#pragma unroll
  for (int jj = 0; jj < 2; ++jj)
#pragma unroll
    for (int g = 0; g < 4; ++g)
      badd[jj][g] = bias[(g * 16 + w * 2 + jj) * 16 + (l & 15)];
#pragma unroll
  for (int mt = 0; mt < 4; ++mt)
#pragma unroll
    for (int jj = 0; jj < 2; ++jj) {
      union { uint16_t s[16]; u32x4 v[2]; } pk;
#pragma unroll
      for (int g = 0; g < 4; ++g)
#pragma unroll
        for (int q = 0; q < 4; ++q)
          pk.s[g * 4 + q] = f2bf(acc[mt][jj][g][q] + badd[jj][g]);
      size_t cell = ((size_t)bb * 128 + (size_t)(sg * 4 + mt)) * 16 + (size_t)(w * 2 + jj);
      char* dst = (char*)xpo + cell * 2048 + (size_t)l * 32;
      *(u32x4*)dst = pk.v[0];
      *(u32x4*)(dst + 16) = pk.v[1];
    }
}

// ---------------------------------------------------------------------------
extern "C" void kernel_launch(void* const* d_in, const int* in_sizes, int n_in,
                              void* d_out, int out_size, void* d_ws, size_t ws_size,
                              hipStream_t stream) {
  const float* x   = (const float*)d_in[0];
  const float* hn  = (const float*)d_in[1];
  const float* cn  = (const float*)d_in[2];
  const float* wih = (const float*)d_in[3];
  const float* whh = (const float*)d_in[4];
  const float* bih = (const float*)d_in[5];
  const float* bhh = (const float*)d_in[6];
  float* out = (float*)d_out;
  char* ws = (char*)d_ws;

  uint16_t* xsp  = (uint16_t*)(ws + XS_OFF);
  uint16_t* wihp = (uint16_t*)(ws + WIH_OFF);
  uint16_t* whhp = (uint16_t*)(ws + WHH_OFF);
  uint16_t* xp0  = (uint16_t*)(ws + XP0_OFF);
  uint16_t* xp1  = (uint16_t*)(ws + XP1_OFF);
  uint16_t* hst  = (uint16_t*)(ws + HST_OFF);
  float*    cst  = (float*)(ws + CST_OFF);
  float*    bias = (float*)(ws + BIAS_OFF);

  hipFuncSetAttribute(reinterpret_cast<const void*>(fused_k),
                      hipFuncAttributeMaxDynamicSharedMemorySize, LDS_BYTES);

  hipLaunchKernelGGL(pack_x_k, dim3(2048), dim3(256), 0, stream, x, hn, xsp);
  hipLaunchKernelGGL(pack_misc_k, dim3(36), dim3(256), 0, stream,
                     wih, whh, bih, bhh, hn, cn, wihp, whhp, bias, hst, cst);
  for (int c = 0; c <= NCHUNK; ++c) {
    int lc = c - 1;
    int gc = (c < NCHUNK) ? c : -1;
    hipLaunchKernelGGL(fused_k, dim3(528), dim3(512), LDS_BYTES, stream,
                       xsp, wihp, whhp, bias, xp0, xp1, hst, cst, out, lc, gc);
  }
}